// Round 20
// baseline (263.770 us; speedup 1.0000x reference)
//
#include <hip/hip_runtime.h>
#include <hip/hip_bf16.h>
#include <math.h>

typedef __attribute__((ext_vector_type(4))) float  f32x4;
typedef __attribute__((ext_vector_type(4))) int    i32x4;
typedef __attribute__((ext_vector_type(8))) __bf16 bf16x8;
typedef __attribute__((ext_vector_type(8))) unsigned short u16x8;
typedef __attribute__((ext_vector_type(4))) unsigned short u16x4;

#define DEV static __device__ __forceinline__

#if __has_builtin(__builtin_amdgcn_permlane32_swap) && __has_builtin(__builtin_amdgcn_permlane16_swap)
#define HAVE_PERMLANE 1
#else
#define HAVE_PERMLANE 0
#endif

namespace {

constexpr int kB = 16, kT1 = 256, kF = 512, kN = 4, kT2 = 1024, kH = 8;
constexpr float kSCALE = 0.125f;                 // 1/sqrt(64)
constexpr float kLOG2E = 1.4426950408889634f;

DEV unsigned short f2bf(float f) {               // native RNE cast (v_cvt_pk-fusable)
  union { __bf16 h; unsigned short u; } c; c.h = (__bf16)f; return c.u;
}
DEV float bf2f(unsigned short h) {
  union { unsigned u; float f; } c; c.u = ((unsigned)h) << 16;
  return c.f;
}

DEV void async_copy16(const void* g, void* l) {
  __builtin_amdgcn_global_load_lds(
      (const __attribute__((address_space(1))) unsigned int*)g,
      (__attribute__((address_space(3))) unsigned int*)l, 16, 0, 0);
}

DEV bf16x8 cvt8(f32x4 lo, f32x4 hi) {            // 8 f32 -> bf16x8 (RNE casts)
  bf16x8 r;
  r[0] = (__bf16)lo[0]; r[1] = (__bf16)lo[1]; r[2] = (__bf16)lo[2]; r[3] = (__bf16)lo[3];
  r[4] = (__bf16)hi[0]; r[5] = (__bf16)hi[1]; r[6] = (__bf16)hi[2]; r[7] = (__bf16)hi[3];
  return r;
}

// ---------------------------------------------------------------------------
// Convert the 4 weight matrices (512x512 f32) to bf16.
// ---------------------------------------------------------------------------
__global__ __launch_bounds__(256) void convert_w(
    const float* __restrict__ w0, const float* __restrict__ w1,
    const float* __restrict__ w2, const float* __restrict__ w3,
    unsigned short* __restrict__ o0, unsigned short* __restrict__ o1,
    unsigned short* __restrict__ o2, unsigned short* __restrict__ o3) {
  const int r = blockIdx.x >> 8;
  const int l = ((blockIdx.x & 255) * 256 + threadIdx.x) * 4;
  const float* src = r == 0 ? w0 : r == 1 ? w1 : r == 2 ? w2 : w3;
  unsigned short* dst = r == 0 ? o0 : r == 1 ? o1 : r == 2 ? o2 : o3;
  const float4 v = *(const float4*)(src + l);
  u16x4 q; q[0] = f2bf(v.x); q[1] = f2bf(v.y); q[2] = f2bf(v.z); q[3] = f2bf(v.w);
  *(u16x4*)(dst + l) = q;
}

// ---------------------------------------------------------------------------
// gemm_kv2: fused K+V projections, 128x256 tile, BK=32, 16 K-iters, 8 waves.
// acc = 4x4 = 64 AGPR -> ~128 total regs -> 2 blocks/CU under (512,4).
// LDS 48 KB. Counted vmcnt: A=2,W=2 loads/tile; top VMW(4) retires W(kt),
// bottom VMW(2) retires A(kt+1). grid = 2048:
// blocks 0..1023: K -> kv layout; 1024..2047: V -> V^T layout.
// (r19 bug: decode used >>11/&2047 with grid 2048 -> rb up to 1023 OOB.)
// ---------------------------------------------------------------------------
__global__ __launch_bounds__(512, 4) void gemm_kv2(
    const float* __restrict__ Ak, const unsigned short* __restrict__ Wk,
    const float* __restrict__ bk, unsigned short* __restrict__ outk,
    const float* __restrict__ Av, const unsigned short* __restrict__ Wv,
    const float* __restrict__ bv, unsigned short* __restrict__ outv_) {
  __shared__ __align__(16) unsigned short As[2][128 * 32];   // 8 KB each
  __shared__ __align__(16) unsigned short Ws[2][256 * 32];   // 16 KB each
  const int t = threadIdx.x, lane = t & 63, wave = t >> 6;
  const int kv = blockIdx.x >> 10;               // 0 = K, 1 = V   (FIXED)
  const int wl = blockIdx.x & 1023;              // 1024 work units per tensor
  const int rb = wl >> 1, cb = wl & 1;           // rb: 0..511, cb: 0..1
  const float* A = kv ? Av : Ak;
  const unsigned short* Wb = kv ? Wv : Wk;
  const float* bias = kv ? bv : bk;
  unsigned short* outv = kv ? outv_ : outk;
  const int wr = wave >> 2, wc = wave & 3;       // 2M x 4N wave grid (64x64 each)
  const int lq = lane & 15, lg = lane >> 4;

  f32x4 acc[4][4];
#pragma unroll
  for (int i = 0; i < 4; ++i)
#pragma unroll
    for (int j = 0; j < 4; ++j) acc[i][j] = f32x4{0.f, 0.f, 0.f, 0.f};

  f32x4 areg[2];
  bf16x8 af[4], bf[4];

#define A_ISSUE(kt)                                                            \
  do {                                                                         \
    _Pragma("unroll")                                                          \
    for (int j_ = 0; j_ < 2; ++j_) {                                           \
      const int sid_ = t + j_ * 512;                                           \
      const int row_ = sid_ >> 3, cs_ = sid_ & 7;                              \
      areg[j_] = *(const f32x4*)(A + (size_t)(rb * 128 + row_) * kF +          \
                                 (kt) * 32 + cs_ * 4);                         \
    }                                                                          \
  } while (0)

  // LDS A [128][32] bf16: full-seg index (cs>>1) XOR-swizzled per row pair.
#define A_WRITE(dst)                                                           \
  do {                                                                         \
    _Pragma("unroll")                                                          \
    for (int j_ = 0; j_ < 2; ++j_) {                                           \
      const int sid_ = t + j_ * 512;                                           \
      const int row_ = sid_ >> 3, cs_ = sid_ & 7;                              \
      const int fs_ = ((cs_ >> 1) ^ ((row_ >> 1) & 3));                        \
      u16x4 pk_;                                                               \
      pk_[0] = f2bf(areg[j_][0]); pk_[1] = f2bf(areg[j_][1]);                  \
      pk_[2] = f2bf(areg[j_][2]); pk_[3] = f2bf(areg[j_][3]);                  \
      *(u16x4*)&(dst)[row_ * 32 + fs_ * 8 + (cs_ & 1) * 4] = pk_;              \
    }                                                                          \
  } while (0)

  // W staging: glds, pre-swizzled source, linear dest.
#define W_ISSUE(kt, dst)                                                       \
  do {                                                                         \
    _Pragma("unroll")                                                          \
    for (int j_ = 0; j_ < 2; ++j_) {                                           \
      const int sid_ = t + j_ * 512;                                           \
      const int row_ = sid_ >> 2, s_ = sid_ & 3;                               \
      async_copy16(Wb + (size_t)(cb * 256 + row_) * kF + (kt) * 32 +           \
                       ((s_ ^ ((row_ >> 1) & 3)) << 3),                        \
                   (dst) + (size_t)sid_ * 8);                                  \
    }                                                                          \
  } while (0)

#define RD_BF(pw)                                                              \
  do {                                                                         \
    _Pragma("unroll")                                                          \
    for (int n_ = 0; n_ < 4; ++n_) {                                           \
      const int br_ = wc * 64 + n_ * 16 + lq;                                  \
      bf[n_] = *(const bf16x8*)&(pw)[br_ * 32 +                                \
                                     ((lg ^ ((br_ >> 1) & 3)) << 3)];          \
    }                                                                          \
  } while (0)

#define RD_AF(pa)                                                              \
  do {                                                                         \
    _Pragma("unroll")                                                          \
    for (int m_ = 0; m_ < 4; ++m_) {                                           \
      const int ar_ = wr * 64 + m_ * 16 + lq;                                  \
      af[m_] = *(const bf16x8*)&(pa)[ar_ * 32 +                                \
                                     ((lg ^ ((ar_ >> 1) & 3)) << 3)];          \
    }                                                                          \
  } while (0)

#define MM16                                                                   \
  do {                                                                         \
    _Pragma("unroll")                                                          \
    for (int m_ = 0; m_ < 4; ++m_)                                             \
      _Pragma("unroll")                                                        \
      for (int n_ = 0; n_ < 4; ++n_)                                           \
        acc[m_][n_] = __builtin_amdgcn_mfma_f32_16x16x32_bf16(                 \
            af[m_], bf[n_], acc[m_][n_], 0, 0, 0);                             \
  } while (0)

#define VMW(n) asm volatile("s_waitcnt vmcnt(" #n ")" ::: "memory")
#define LKW  asm volatile("s_waitcnt lgkmcnt(0)" ::: "memory")
#define SB   __builtin_amdgcn_sched_barrier(0)
#define BAR  do { __builtin_amdgcn_s_barrier(); __builtin_amdgcn_sched_barrier(0); } while (0)

  unsigned short *pa = As[0], *qa = As[1], *pw = Ws[0], *qw = Ws[1];

  // prologue: A(0) [2 loads], W(0) [2 glds] -> out=4
  A_ISSUE(0); W_ISSUE(0, pw);
  VMW(2); SB;                    // A(0) landed; W(0) 2 in flight
  A_WRITE(pa);
  LKW;

#pragma unroll 1
  for (int kt = 0; kt < 16; ++kt) {
    if (kt < 15) {
      A_ISSUE(kt + 1);           // 2 loads -> out = 4
      W_ISSUE(kt + 1, qw);       // 2 glds  -> out = 6
      VMW(4); SB;                // retires W(kt); A(kt+1)+W(kt+1) in flight
    } else {
      VMW(0); SB;                // final W(15) drain
    }
    BAR;                         // publish A(kt)+W(kt) block-wide
    RD_BF(pw); RD_AF(pa);        // 8 ds_read_b128
    LKW; SB;
    __builtin_amdgcn_s_setprio(1); MM16; __builtin_amdgcn_s_setprio(0); SB;
    if (kt < 15) {
      VMW(2); SB;                // A(kt+1) landed; W(kt+1) stays in flight
      A_WRITE(qa);
    }
    LKW; BAR;                    // A-write published; safe buffer rotation
    { unsigned short* x = pa; pa = qa; qa = x; }
    { unsigned short* x = pw; pw = qw; qw = x; }
  }

#undef A_ISSUE
#undef A_WRITE
#undef W_ISSUE
#undef RD_BF
#undef RD_AF
#undef MM16
#undef VMW
#undef LKW
#undef SB
#undef BAR

  float bs4[4];
#pragma unroll
  for (int n = 0; n < 4; ++n) bs4[n] = bias[cb * 256 + wc * 64 + n * 16 + lq];

#pragma unroll
  for (int m = 0; m < 4; ++m) {
    const int row0 = rb * 128 + wr * 64 + m * 16 + lg * 4;
    const int bn = row0 >> 10, t2 = row0 & 1023;
#pragma unroll
    for (int n = 0; n < 4; ++n) {
      const int col = cb * 256 + wc * 64 + n * 16 + lq;
      const int h = col >> 6, d = col & 63;
      if (kv) {                  // V: V^T layout [bn][h][d][t2], packed store
        u16x4 pv;
#pragma unroll
        for (int j = 0; j < 4; ++j) pv[j] = f2bf(acc[m][n][j] + bs4[n]);
        *(u16x4*)&outv[(((size_t)(bn * kH + h)) * 64 + d) * kT2 + t2] = pv;
      } else {                   // K: kv layout [bn][h][t2][64]
#pragma unroll
        for (int j = 0; j < 4; ++j)
          outv[(((size_t)(bn * kH + h)) * kT2 + t2 + j) * 64 + d] =
              f2bf(acc[m][n][j] + bs4[n]);
      }
    }
  }
}

// ---------------------------------------------------------------------------
// gemm_mixed (128x128, BK=64): used for the small GEMMs (Q: MODE 0, O: MODE 2).
// ---------------------------------------------------------------------------
template<int MODE>
__global__ __launch_bounds__(256, 2) void gemm_mixed(
    const float* __restrict__ A, const unsigned short* __restrict__ Wb,
    const float* __restrict__ bias, void* __restrict__ outv, int nrb) {
  __shared__ __align__(16) unsigned short As[2][128 * 64];   // bf16, 16KB each
  __shared__ __align__(16) unsigned short Bs[3][128 * 64];   // bf16, 16KB each
  const int t = threadIdx.x, lane = t & 63, wave = t >> 6;
  const int w = blockIdx.x;
  const int xcd = w & 7, s = w >> 3;
  const int rb = xcd * (nrb >> 3) + (s >> 2);   // cb-siblings adjacent, same XCD
  const int cb = s & 3;
  const int wr = wave >> 1, wc = wave & 1;
  const int lq = lane & 15, lg = lane >> 4;

  const int arow = t >> 1, ah = (t & 1) * 4;    // staging row, seg-base (0|4)
  const float* aptr = A + (size_t)(rb * 128 + arow) * kF + ah * 8;

  f32x4 acc[4][4];
#pragma unroll
  for (int i = 0; i < 4; ++i)
#pragma unroll
    for (int j = 0; j < 4; ++j) acc[i][j] = f32x4{0.f, 0.f, 0.f, 0.f};

  f32x4 arA[8], arB[8];          // two named A issue-buffers (no runtime idx)
  bf16x8 af[4][2], bfr[4][2];

#define A_LOAD(kb, ar)                                                          \
  do {                                                                          \
    const f32x4* p_ = (const f32x4*)(aptr + (kb) * 64);                         \
    ar[0]=p_[0]; ar[1]=p_[1]; ar[2]=p_[2]; ar[3]=p_[3];                         \
    ar[4]=p_[4]; ar[5]=p_[5]; ar[6]=p_[6]; ar[7]=p_[7];                         \
  } while (0)

#define A_CVT(ar, dst)                                                          \
  do {                                                                          \
    _Pragma("unroll")                                                           \
    for (int j_ = 0; j_ < 4; ++j_)                                              \
      *(bf16x8*)&(dst)[arow * 64 + (((ah + j_) ^ (arow & 7)) << 3)] =           \
          cvt8(ar[2*j_], ar[2*j_+1]);                                           \
  } while (0)

#define W_STAGE2(kb, dst)                                                       \
  do {                                                                          \
    _Pragma("unroll")                                                           \
    for (int i_ = 0; i_ < 4; ++i_) {                                            \
      const int sidx_ = t + i_ * 256;                                           \
      const int row_ = sidx_ >> 3;                                              \
      const int gseg_ = (sidx_ & 7) ^ (row_ & 7);                               \
      async_copy16(Wb + (size_t)(cb * 128 + row_) * kF + (kb) * 64 + gseg_ * 8, \
                   (dst) + (size_t)(i_ * 256 + wave * 64) * 8);                 \
    }                                                                           \
  } while (0)

#define FRAG(Ap, Wp)                                                            \
  do {                                                                          \
    _Pragma("unroll")                                                           \
    for (int m_ = 0; m_ < 4; ++m_) {                                            \
      const int ar_ = wr * 64 + m_ * 16 + lq, x7_ = ar_ & 7;                    \
      af[m_][0] = *(const bf16x8*)&(Ap)[ar_ * 64 + ((lg       ^ x7_) << 3)];    \
      af[m_][1] = *(const bf16x8*)&(Ap)[ar_ * 64 + (((lg + 4) ^ x7_) << 3)];    \
    }                                                                           \
    _Pragma("unroll")                                                           \
    for (int n_ = 0; n_ < 4; ++n_) {                                            \
      const int br_ = wc * 64 + n_ * 16 + lq, x7_ = br_ & 7;                    \
      bfr[n_][0] = *(const bf16x8*)&(Wp)[br_ * 64 + ((lg       ^ x7_) << 3)];   \
      bfr[n_][1] = *(const bf16x8*)&(Wp)[br_ * 64 + (((lg + 4) ^ x7_) << 3)];   \
    }                                                                           \
  } while (0)

#define MFMA8                                                                   \
  do {                                                                          \
    _Pragma("unroll")                                                           \
    for (int kk_ = 0; kk_ < 2; ++kk_)                                           \
      _Pragma("unroll")                                                         \
      for (int m_ = 0; m_ < 4; ++m_)                                            \
        _Pragma("unroll")                                                       \
        for (int n_ = 0; n_ < 4; ++n_)                                          \
          acc[m_][n_] = __builtin_amdgcn_mfma_f32_16x16x32_bf16(                \
              af[m_][kk_], bfr[n_][kk_], acc[m_][n_], 0, 0, 0);                 \
  } while (0)

#define VMW(n) asm volatile("s_waitcnt vmcnt(" #n ")" ::: "memory")
#define LKW    asm volatile("s_waitcnt lgkmcnt(0)" ::: "memory")
#define BAR    do { __builtin_amdgcn_s_barrier(); __builtin_amdgcn_sched_barrier(0); } while (0)

  // prologue: A0->arA, A1->arB, W0, W1 (24 in flight)
  A_LOAD(0, arA); A_LOAD(1, arB);
  W_STAGE2(0, Bs[0]); W_STAGE2(1, Bs[1]);
  VMW(16);                       // A0 landed
  A_CVT(arA, As[0]);
  LKW; BAR;
  // iter 0
  A_LOAD(2, arA); W_STAGE2(2, Bs[2]);
  FRAG(As[0], Bs[0]); MFMA8;
  VMW(12); A_CVT(arB, As[1]); LKW; BAR;
  // iter 1
  A_LOAD(3, arB); W_STAGE2(3, Bs[0]);
  FRAG(As[1], Bs[1]); MFMA8;
  VMW(12); A_CVT(arA, As[0]); LKW; BAR;
  // iter 2
  A_LOAD(4, arA); W_STAGE2(4, Bs[1]);
  FRAG(As[0], Bs[2]); MFMA8;
  VMW(12); A_CVT(arB, As[1]); LKW; BAR;
  // iter 3
  A_LOAD(5, arB); W_STAGE2(5, Bs[2]);
  FRAG(As[1], Bs[0]); MFMA8;
  VMW(12); A_CVT(arA, As[0]); LKW; BAR;
  // iter 4
  A_LOAD(6, arA); W_STAGE2(6, Bs[0]);
  FRAG(As[0], Bs[1]); MFMA8;
  VMW(12); A_CVT(arB, As[1]); LKW; BAR;
  // iter 5
  A_LOAD(7, arB); W_STAGE2(7, Bs[1]);
  FRAG(As[1], Bs[2]); MFMA8;
  VMW(12); A_CVT(arA, As[0]); LKW; BAR;
  // iter 6
  FRAG(As[0], Bs[0]); MFMA8;
  VMW(0); A_CVT(arB, As[1]); LKW; BAR;
  // iter 7
  FRAG(As[1], Bs[1]); MFMA8;

#undef A_LOAD
#undef A_CVT
#undef W_STAGE2
#undef FRAG
#undef MFMA8
#undef VMW
#undef LKW
#undef BAR

  float bs[4];
#pragma unroll
  for (int n2 = 0; n2 < 4; ++n2) bs[n2] = bias[cb*128 + wc*64 + n2*16 + lq];

#pragma unroll
  for (int m = 0; m < 4; ++m) {
#pragma unroll
    for (int n2 = 0; n2 < 4; ++n2) {
      const int col = cb*128 + wc*64 + n2*16 + lq;
      const int row0 = rb*128 + wr*64 + m*16 + lg*4;
#pragma unroll
      for (int j = 0; j < 4; ++j) {
        const int row = row0 + j;
        const float v = acc[m][n2][j] + bs[n2];
        if (MODE == 2) {
          ((float*)outv)[(size_t)row * kF + col] = v;
        } else {
          const int h = col >> 6, d = col & 63;
          const int b = row >> 8, t1i = row & 255;
          ((unsigned short*)outv)[(((size_t)(b * kH + h)) * kT1 + t1i) * 64 + d] = f2bf(v);
        }
      }
    }
  }
}

// ---------------------------------------------------------------------------
// Stage-1 flash attention, q-split x2: one block per (b,n,h,qb), 8 waves x
// 16 q-rows = 128 q-rows/block. NO-MAX softmax, lane-local l1, 3-buffer K/V
// (52 KB -> 3 blocks/CU), stage-at-bottom + wait-before-barrier vmcnt(2).
// grid = 1024, XCD-swizzled so qb-siblings share an XCD (K/V L2 reuse).
// ---------------------------------------------------------------------------
__global__ __launch_bounds__(512, 4) void attn_kernel(
    const unsigned short* __restrict__ qh, const unsigned short* __restrict__ kh,
    const unsigned short* __restrict__ vt, const int* __restrict__ mask_audio,
    unsigned short* __restrict__ phone) {
  __shared__ __align__(16) unsigned short Ks[3][64 * 64];   // 3 x 8 KB
  __shared__ __align__(16) unsigned short Vs[3][64 * 64];   // 3 x 8 KB
  __shared__ float Mbias[1024];                              // 4 KB
  const int t = threadIdx.x;
  const int lane = t & 63, wave = t >> 6;
  const int lq = lane & 15, lg = lane >> 4;
  const int w = blockIdx.x;
  const int swz = (w & 7) * 128 + (w >> 3);     // bijective (1024 % 8 == 0)
  const int qb = swz & 1, bnh = swz >> 1;
  const int h = bnh & 7, n = (bnh >> 3) & 3, b = bnh >> 5;
  const size_t qbase  = ((size_t)(b * kH + h)) * kT1 * 64;
  const size_t kvbase = ((size_t)((b * kN + n) * kH + h)) * kT2 * 64;  // same for vt
  const int* mbase = mask_audio + (size_t)(b * kN + n) * kT2;

  const int srow = (wave << 3) + (lane >> 3);   // staging row 0..63
  const int sgx = ((lane & 7) ^ (srow & 7)) << 3;  // pre-swizzled global seg (u16)

#define STAGE_KV(c, kd, vd)                                                       \
  do {                                                                            \
    async_copy16(kh + kvbase + ((size_t)(((c) << 6) + srow) << 6) + sgx,          \
                 (kd) + (wave << 9));                                             \
    async_copy16(vt + kvbase + ((size_t)srow << 10) + ((c) << 6) + sgx,           \
                 (vd) + (wave << 9));                                             \
  } while (0)

  { // mask -> additive f32 bias, loaded once for all 16 chunks
    const int i0 = t * 2;
    const int m0 = mbase[i0], m1 = mbase[i0 + 1];
    Mbias[i0]     = m0 ? 0.f : -1e30f;
    Mbias[i0 + 1] = m1 ? 0.f : -1e30f;
  }

  // Q fragments in registers (16 rows per wave; reused all 16 chunks)
  bf16x8 qf0, qf1;
  {
    const unsigned short* qp = qh + qbase +
        ((size_t)((qb << 7) + (wave << 4) + lq) << 6);
    qf0 = *(const bf16x8*)(qp + (lg << 3));
    qf1 = *(const bf16x8*)(qp + 32 + (lg << 3));
  }

  unsigned short *kb0 = Ks[0], *kb1 = Ks[1], *kb2 = Ks[2];
  unsigned short *vb0 = Vs[0], *vb1 = Vs[1], *vb2 = Vs[2];

  // prologue: stage chunks 0,1 (4 loads in flight); drain mask ds_writes
  STAGE_KV(0, kb0, vb0);
  STAGE_KV(1, kb1, vb1);
  asm volatile("s_waitcnt lgkmcnt(0)" ::: "memory");

  f32x4 of[4];
  float l1 = 0.f;
#pragma unroll
  for (int fd = 0; fd < 4; ++fd) of[fd] = f32x4{0.f, 0.f, 0.f, 0.f};
  const float sc2 = kSCALE * kLOG2E;

#pragma unroll 1
  for (int c = 0; c < 16; ++c) {
    // wait-before-barrier: retire chunk c's 2 loads (mine), publish via barrier
    if (c < 15) asm volatile("s_waitcnt vmcnt(2)" ::: "memory");
    else        asm volatile("s_waitcnt vmcnt(0)" ::: "memory");
    __builtin_amdgcn_s_barrier();
    __builtin_amdgcn_sched_barrier(0);

    const float* mrow = Mbias + (c << 6);

    f32x4 sT[4];
#pragma unroll
    for (int kt = 0; kt < 4; ++kt) {
      const int kr = kt * 16 + lq, x7 = kr & 7;
      const bf16x8 kf0 = *(const bf16x8*)&kb0[kr * 64 + ((lg       ^ x7) << 3)];
      const bf16x8 kf1 = *(const bf16x8*)&kb0[kr * 64 + (((lg + 4) ^ x7) << 3)];
      f32x4 sv = f32x4{0.f, 0.f, 0.f, 0.f};
      sv = __builtin_amdgcn_mfma_f32_16x16x32_bf16(kf0, qf0, sv, 0, 0, 0);
      sv = __builtin_amdgcn_mfma_f32_16x16x32_bf16(kf1, qf1, sv, 0, 0, 0);
      sT[kt] = sv;   // lane: q=lq, key = kt*16 + lg*4 + j
    }
    // no-max softmax: P = exp2(scale*s + bias); bounded, no overflow risk
    float pf[16];
#pragma unroll
    for (int kt = 0; kt < 4; ++kt) {
      const f32x4 mk = *(const f32x4*)&mrow[kt * 16 + lg * 4];
#pragma unroll
      for (int j = 0; j < 4; ++j)
        pf[kt*4+j] = exp2f(fmaf(sT[kt][j], sc2, mk[j]));
    }
    const float a0 = (pf[0] + pf[1]) + (pf[2] + pf[3]);
    const float a1 = (pf[4] + pf[5]) + (pf[6] + pf[7]);
    const float a2 = (pf[8] + pf[9]) + (pf[10] + pf[11]);
    const float a3 = (pf[12] + pf[13]) + (pf[14] + pf[15]);
    l1 += (a0 + a1) + (a2 + a3);               // lane-local; reduced at end
    // repack P (S^T layout) -> PV A-fragments (native casts -> cvt_pk)
    unsigned pk[8];
#pragma unroll
    for (int kt = 0; kt < 4; ++kt) {
      pk[2*kt]   = (unsigned)f2bf(pf[4*kt+0]) | ((unsigned)f2bf(pf[4*kt+1]) << 16);
      pk[2*kt+1] = (unsigned)f2bf(pf[4*kt+2]) | ((unsigned)f2bf(pf[4*kt+3]) << 16);
    }
    unsigned am0[4], am1[4];
#if HAVE_PERMLANE
    {
      auto x0p = __builtin_amdgcn_permlane32_swap((int)pk[0], (int)pk[2], false, false);
      auto y0p = __builtin_amdgcn_permlane16_swap(x0p[0], x0p[1], false, false);
      am0[0] = (unsigned)y0p[0]; am0[2] = (unsigned)y0p[1];
      auto x1p = __builtin_amdgcn_permlane32_swap((int)pk[1], (int)pk[3], false, false);
      auto y1p = __builtin_amdgcn_permlane16_swap(x1p[0], x1p[1], false, false);
      am0[1] = (unsigned)y1p[0]; am0[3] = (unsigned)y1p[1];
      auto x2p = __builtin_amdgcn_permlane32_swap((int)pk[4], (int)pk[6], false, false);
      auto y2p = __builtin_amdgcn_permlane16_swap(x2p[0], x2p[1], false, false);
      am1[0] = (unsigned)y2p[0]; am1[2] = (unsigned)y2p[1];
      auto x3p = __builtin_amdgcn_permlane32_swap((int)pk[5], (int)pk[7], false, false);
      auto y3p = __builtin_amdgcn_permlane16_swap(x3p[0], x3p[1], false, false);
      am1[1] = (unsigned)y3p[0]; am1[3] = (unsigned)y3p[1];
    }
#else
    {
      const int srcbase = (2 * (lg & 1)) * 16 + lq;
#pragma unroll
      for (int u = 0; u < 4; ++u) {
        const int src = srcbase + (u >> 1) * 16;
        const unsigned va0 = __shfl(pk[(u & 1)],     src);
        const unsigned vb0s = __shfl(pk[2 + (u & 1)], src);
        am0[u] = (lg & 2) ? vb0s : va0;
        const unsigned va1 = __shfl(pk[4 + (u & 1)], src);
        const unsigned vb1s = __shfl(pk[6 + (u & 1)], src);
        am1[u] = (lg & 2) ? vb1s : va1;
      }
    }
#endif
    union { unsigned u[4]; bf16x8 v; } A0, A1;
#pragma unroll
    for (int u = 0; u < 4; ++u) { A0.u[u] = am0[u]; A1.u[u] = am1[u]; }
#pragma unroll
    for (int fd = 0; fd < 4; ++fd) {
      const int d = fd * 16 + lq, x7d = d & 7;
      const bf16x8 vB0 = *(const bf16x8*)&vb0[d * 64 + ((lg       ^ x7d) << 3)];
      const bf16x8 vB1 = *(const bf16x8*)&vb0[d * 64 + (((lg + 4) ^ x7d) << 3)];
      of[fd] = __builtin_amdgcn_mfma_f32_16x16x32_bf16(A0.v, vB0, of[fd], 0, 0, 0);
      of[fd] = __builtin_amdgcn_mfma_f32_16x16x32_bf16(A1.v, vB1, of[fd], 0, 0, 0);
    }

    // stage chunk c+2 at bottom (covers ~1.5 iterations before its wait)
    if (c < 14) STAGE_KV(c + 2, kb2, vb2);
    { unsigned short* x = kb0; kb0 = kb1; kb1 = kb2; kb2 = x; }
    { unsigned short* x = vb0; vb0 = vb1; vb1 = vb2; vb2 = x; }
  }
#undef STAGE_KV

  // epilogue: cross-lane l1 reduce (once), then normalize + store
  l1 += __shfl_xor(l1, 16);
  l1 += __shfl_xor(l1, 32);
  const size_t phbase = ((size_t)((b * kN + n) * kH + h)) * kT1 * 64;
  const float li0 = 1.f / __shfl(l1, lg*4 + 0);
  const float li1 = 1.f / __shfl(l1, lg*4 + 1);
  const float li2 = 1.f / __shfl(l1, lg*4 + 2);
  const float li3 = 1.f / __shfl(l1, lg*4 + 3);
#pragma unroll
  for (int fd = 0; fd < 4; ++fd) {
    const int d = fd * 16 + lq;
    const size_t rowb = phbase +
        (size_t)((qb << 7) + (wave << 4) + lg*4) * 64 + d;
    phone[rowb]       = f2bf(of[fd][0] * li0);
    phone[rowb + 64]  = f2bf(of[fd][1] * li1);
    phone[rowb + 128] = f2bf(of[fd][2] * li2);
    phone[rowb + 192] = f2bf(of[fd][3] * li3);
  }
}

// ---------------------------------------------------------------------------
// Stage-2: per (b,t1,h) wave: masked softmax over N=4 candidates.
// ---------------------------------------------------------------------------
__global__ __launch_bounds__(256) void stage2_kernel(
    const unsigned short* __restrict__ qh, const unsigned short* __restrict__ phone,
    const int* __restrict__ mask_spk, float* __restrict__ x) {
  const int t = threadIdx.x, lane = t & 63, wave = t >> 6;
  const int wid = blockIdx.x * 4 + wave;
  const int h = wid & 7;
  const int bt = wid >> 3;
  const int t1i = bt & 255, b = bt >> 8;
  const int d = lane;
  const float q = bf2f(qh[(((size_t)(b * kH + h)) * kT1 + t1i) * 64 + d]);
  float ph[4], ss[4];
#pragma unroll
  for (int n = 0; n < 4; ++n) {
    ph[n] = bf2f(phone[(((size_t)((b * kN + n) * kH + h)) * kT1 + t1i) * 64 + d]);
    float sv = q * ph[n];
#pragma unroll
    for (int o = 1; o < 64; o <<= 1) sv += __shfl_xor(sv, o);
    ss[n] = sv * kSCALE;
  }
  int msk[4];
#pragma unroll
  for (int n = 0; n < 4; ++n) msk[n] = mask_spk[b * kN + n];
  float mx = -INFINITY;
#pragma unroll
  for (int n = 0; n < 4; ++n) if (msk[n]) mx = fmaxf(mx, ss[n]);
  float e[4], sum = 0.f;
#pragma unroll
  for (int n = 0; n < 4; ++n) { const float v = msk[n] ? __expf(ss[n] - mx) : 0.f; e[n] = v; sum += v; }
  float xo = 0.f;
#pragma unroll
  for (int n = 0; n < 4; ++n) xo += e[n] * ph[n];
  xo /= sum;
  x[((size_t)(b * kT1 + t1i)) * kF + h * 64 + d] = xo;
}

}  // namespace

// ---------------------------------------------------------------------------
extern "C" void kernel_launch(void* const* d_in, const int* in_sizes, int n_in,
                              void* d_out, int out_size, void* d_ws, size_t ws_size,
                              hipStream_t stream) {
  (void)in_sizes; (void)n_in; (void)out_size; (void)ws_size;
  const float* query = (const float*)d_in[0];
  const float* key   = (const float*)d_in[1];
  const float* value = (const float*)d_in[2];
  const int* mask_audio = (const int*)d_in[3];
  const int* mask_spk   = (const int*)d_in[4];
  const float* Wq = (const float*)d_in[5];  const float* bq = (const float*)d_in[6];
  const float* Wk = (const float*)d_in[7];  const float* bk = (const float*)d_in[8];
  const float* Wv = (const float*)d_in[9];  const float* bv = (const float*)d_in[10];
  const float* Wo = (const float*)d_in[11]; const float* bo = (const float*)d_in[12];
  float* out = (float*)d_out;

  // workspace layout (~158 MB)
  unsigned short* qws  = (unsigned short*)d_ws;                       // 2,097,152 u16
  unsigned short* kws  = qws  + (size_t)kB * kH * kT1 * 64;           // 33,554,432 u16
  unsigned short* vws  = kws  + (size_t)kB * kN * kH * kT2 * 64;      // 33,554,432 u16 (V^T)
  unsigned short* phws = vws  + (size_t)kB * kN * kH * kT2 * 64;      // 8,388,608 u16
  float*          xws  = (float*)(phws + (size_t)kB * kN * kH * kT1 * 64);  // 2,097,152 f32
  unsigned short* wqb  = (unsigned short*)(xws + (size_t)kB * kT1 * kF);
  unsigned short* wkb  = wqb + (size_t)kF * kF;
  unsigned short* wvb  = wkb + (size_t)kF * kF;
  unsigned short* wob  = wvb + (size_t)kF * kF;

  convert_w<<<1024, 256, 0, stream>>>(Wq, Wk, Wv, Wo, wqb, wkb, wvb, wob);
  gemm_mixed<0><<<kB * kT1 / 128 * 4, 256, 0, stream>>>(query, wqb, bq, qws, kB * kT1 / 128);
  gemm_kv2<<<2048, 512, 0, stream>>>(
      key, wkb, bk, kws, value, wvb, bv, vws);
  attn_kernel<<<kB * kN * kH * 2, 512, 0, stream>>>(qws, kws, vws, mask_audio, phws);
  stage2_kernel<<<kB * kT1 * kH / 4, 256, 0, stream>>>(qws, phws, mask_spk, xws);
  gemm_mixed<2><<<kB * kT1 / 128 * 4, 256, 0, stream>>>(xws, wob, bo, out, kB * kT1 / 128);
}

// Round 21
// 249.469 us; speedup vs baseline: 1.0573x; 1.0573x over previous
//
#include <hip/hip_runtime.h>
#include <hip/hip_bf16.h>
#include <math.h>

typedef __attribute__((ext_vector_type(4))) float  f32x4;
typedef __attribute__((ext_vector_type(4))) int    i32x4;
typedef __attribute__((ext_vector_type(8))) __bf16 bf16x8;
typedef __attribute__((ext_vector_type(8))) unsigned short u16x8;
typedef __attribute__((ext_vector_type(4))) unsigned short u16x4;

#define DEV static __device__ __forceinline__

#if __has_builtin(__builtin_amdgcn_permlane32_swap) && __has_builtin(__builtin_amdgcn_permlane16_swap)
#define HAVE_PERMLANE 1
#else
#define HAVE_PERMLANE 0
#endif

namespace {

constexpr int kB = 16, kT1 = 256, kF = 512, kN = 4, kT2 = 1024, kH = 8;
constexpr float kSCALE = 0.125f;                 // 1/sqrt(64)
constexpr float kLOG2E = 1.4426950408889634f;

DEV unsigned short f2bf(float f) {               // native RNE cast (v_cvt_pk-fusable)
  union { __bf16 h; unsigned short u; } c; c.h = (__bf16)f; return c.u;
}
DEV float bf2f(unsigned short h) {
  union { unsigned u; float f; } c; c.u = ((unsigned)h) << 16;
  return c.f;
}

DEV void async_copy16(const void* g, void* l) {
  __builtin_amdgcn_global_load_lds(
      (const __attribute__((address_space(1))) unsigned int*)g,
      (__attribute__((address_space(3))) unsigned int*)l, 16, 0, 0);
}

DEV bf16x8 cvt8(f32x4 lo, f32x4 hi) {            // 8 f32 -> bf16x8 (RNE casts)
  bf16x8 r;
  r[0] = (__bf16)lo[0]; r[1] = (__bf16)lo[1]; r[2] = (__bf16)lo[2]; r[3] = (__bf16)lo[3];
  r[4] = (__bf16)hi[0]; r[5] = (__bf16)hi[1]; r[6] = (__bf16)hi[2]; r[7] = (__bf16)hi[3];
  return r;
}

// ---------------------------------------------------------------------------
// Convert the 4 weight matrices (512x512 f32) to bf16.
// ---------------------------------------------------------------------------
__global__ __launch_bounds__(256) void convert_w(
    const float* __restrict__ w0, const float* __restrict__ w1,
    const float* __restrict__ w2, const float* __restrict__ w3,
    unsigned short* __restrict__ o0, unsigned short* __restrict__ o1,
    unsigned short* __restrict__ o2, unsigned short* __restrict__ o3) {
  const int r = blockIdx.x >> 8;
  const int l = ((blockIdx.x & 255) * 256 + threadIdx.x) * 4;
  const float* src = r == 0 ? w0 : r == 1 ? w1 : r == 2 ? w2 : w3;
  unsigned short* dst = r == 0 ? o0 : r == 1 ? o1 : r == 2 ? o2 : o3;
  const float4 v = *(const float4*)(src + l);
  u16x4 q; q[0] = f2bf(v.x); q[1] = f2bf(v.y); q[2] = f2bf(v.z); q[3] = f2bf(v.w);
  *(u16x4*)(dst + l) = q;
}

// ---------------------------------------------------------------------------
// gemm256_kv: K and V projections FUSED into one 1024-block launch (blocks
// 0-511: K -> kv layout; 512-1023: V -> V^T layout). Removes the inter-kernel
// drain/tail between two 512-block launches. 256x256 tile, BK=64, 8 waves,
// 2 MFMA phases/K-tile, counted vmcnt (12 loads in flight across barriers).
// (512,2): 128 VGPR + 128 acc-AGPR fills the 256-reg budget exactly ->
// 1 block/CU. Measured alternatives all lose: deeper prefetch (r15) and
// 2-blocks/CU at 256^2 (r16) spill; BK=32 128x256 2-blocks/CU (r20) trades
// occupancy for 2x barrier overhead and is ~19% slower. This is the
// empirical optimum of the explored design space.
// ---------------------------------------------------------------------------
__global__ __launch_bounds__(512, 2) void gemm256_kv(
    const float* __restrict__ Ak, const unsigned short* __restrict__ Wk,
    const float* __restrict__ bk, unsigned short* __restrict__ outk,
    const float* __restrict__ Av, const unsigned short* __restrict__ Wv,
    const float* __restrict__ bv, unsigned short* __restrict__ outv_) {
  __shared__ __align__(16) unsigned short As[2][256 * 64];   // 32 KB each
  __shared__ __align__(16) unsigned short Ws[2][256 * 64];   // 32 KB each
  const int t = threadIdx.x, lane = t & 63, wave = t >> 6;
  const int kv = blockIdx.x >> 9;                // 0 = K, 1 = V
  const int wl = blockIdx.x & 511;
  const int rb = wl >> 1, cb = wl & 1;
  const float* A = kv ? Av : Ak;
  const unsigned short* Wb = kv ? Wv : Wk;
  const float* bias = kv ? bv : bk;
  unsigned short* outv = kv ? outv_ : outk;
  const int wr = wave >> 2, wc = wave & 3;       // 2M x 4N wave grid
  const int lq = lane & 15, lg = lane >> 4;
  const int arg = t >> 4, as16 = t & 15;         // A staging: rowgrp, 16B seg

  f32x4 acc[8][4];
#pragma unroll
  for (int i = 0; i < 8; ++i)
#pragma unroll
    for (int j = 0; j < 4; ++j) acc[i][j] = f32x4{0.f, 0.f, 0.f, 0.f};

  f32x4 areg[8];
  bf16x8 af[4][2], bf[4][2];

#define A_ISSUE(kt)                                                             \
  do {                                                                          \
    _Pragma("unroll")                                                           \
    for (int j_ = 0; j_ < 8; ++j_)                                              \
      areg[j_] = *(const f32x4*)(A + (size_t)(rb * 256 + j_ * 32 + arg) * kF +  \
                                 (kt) * 64 + as16 * 4);                         \
  } while (0)

#define A_WRITE(dst)                                                            \
  do {                                                                          \
    _Pragma("unroll")                                                           \
    for (int j_ = 0; j_ < 8; ++j_) {                                            \
      const int row_ = j_ * 32 + arg;                                           \
      const int off_ = row_ * 64 + (((as16 >> 1) ^ (row_ & 7)) << 3) + (as16 & 1) * 4; \
      u16x4 pk_;                                                                \
      pk_[0] = f2bf(areg[j_][0]); pk_[1] = f2bf(areg[j_][1]);                   \
      pk_[2] = f2bf(areg[j_][2]); pk_[3] = f2bf(areg[j_][3]);                   \
      *(u16x4*)&(dst)[off_] = pk_;                                              \
    }                                                                           \
  } while (0)

#define W_ISSUE(kt, dst)                                                        \
  do {                                                                          \
    _Pragma("unroll")                                                           \
    for (int j_ = 0; j_ < 4; ++j_) {                                            \
      const int sidx_ = t + j_ * 512;                                           \
      const int row_ = sidx_ >> 3, s_ = sidx_ & 7;                              \
      async_copy16(Wb + (size_t)(cb * 256 + row_) * kF + (kt) * 64 +            \
                       ((s_ ^ (row_ & 7)) << 3),                                \
                   (dst) + (size_t)(j_ * 512 + wave * 64) * 8);                 \
    }                                                                           \
  } while (0)

#define RD_BF(pw)                                                               \
  do {                                                                          \
    _Pragma("unroll")                                                           \
    for (int n_ = 0; n_ < 4; ++n_) {                                            \
      const int br_ = wc * 64 + n_ * 16 + lq, x7_ = br_ & 7;                    \
      bf[n_][0] = *(const bf16x8*)&(pw)[br_ * 64 + ((lg ^ x7_) << 3)];          \
      bf[n_][1] = *(const bf16x8*)&(pw)[br_ * 64 + (((4 + lg) ^ x7_) << 3)];    \
    }                                                                           \
  } while (0)

#define RD_AF(pa, mb)                                                           \
  do {                                                                          \
    _Pragma("unroll")                                                           \
    for (int m_ = 0; m_ < 4; ++m_) {                                            \
      const int ar_ = wr * 128 + ((mb) + m_) * 16 + lq, x7_ = ar_ & 7;          \
      af[m_][0] = *(const bf16x8*)&(pa)[ar_ * 64 + ((lg ^ x7_) << 3)];          \
      af[m_][1] = *(const bf16x8*)&(pa)[ar_ * 64 + (((4 + lg) ^ x7_) << 3)];    \
    }                                                                           \
  } while (0)

#define MM(mb)                                                                  \
  do {                                                                          \
    _Pragma("unroll")                                                           \
    for (int kk_ = 0; kk_ < 2; ++kk_)                                           \
      _Pragma("unroll")                                                         \
      for (int m_ = 0; m_ < 4; ++m_)                                            \
        _Pragma("unroll")                                                       \
        for (int n_ = 0; n_ < 4; ++n_)                                          \
          acc[(mb) + m_][n_] = __builtin_amdgcn_mfma_f32_16x16x32_bf16(         \
              af[m_][kk_], bf[n_][kk_], acc[(mb) + m_][n_], 0, 0, 0);           \
  } while (0)

#define VMW(n) asm volatile("s_waitcnt vmcnt(" #n ")" ::: "memory")
#define LKW  asm volatile("s_waitcnt lgkmcnt(0)" ::: "memory")
#define SB   __builtin_amdgcn_sched_barrier(0)
#define BAR  do { __builtin_amdgcn_s_barrier(); __builtin_amdgcn_sched_barrier(0); } while (0)

  // prologue: A(0)->regs, W(0)->LDS (12 in flight)
  A_ISSUE(0); W_ISSUE(0, Ws[0]);
  VMW(4); SB;                    // A(0) landed; W(0) 4 in flight
  A_WRITE(As[0]);
  LKW;

  unsigned short *pa = As[0], *qa = As[1], *pw = Ws[0], *qw = Ws[1];
#pragma unroll 1
  for (int kt = 0; kt < 8; ++kt) {
    if (kt < 7) {
      A_ISSUE(kt + 1);           // 8 loads
      W_ISSUE(kt + 1, qw);       // 4 glds -> out = 4 + 12
      VMW(12); SB;               // my W(kt) landed; 12 stay in flight
    } else {
      VMW(0); SB;                // final W(7) drain
    }
    BAR;                         // publish A(kt)+W(kt) block-wide
    // phase 1: C rows m0..3
    RD_BF(pw); RD_AF(pa, 0);
    LKW; SB;
    __builtin_amdgcn_s_setprio(1); MM(0); __builtin_amdgcn_s_setprio(0); SB;
    // phase 2: C rows m4..7
    RD_AF(pa, 4);
    LKW; SB;
    __builtin_amdgcn_s_setprio(1); MM(4); __builtin_amdgcn_s_setprio(0); SB;
    if (kt < 7) {
      VMW(4); SB;                // A(kt+1) landed; W(kt+1) stays in flight
      A_WRITE(qa);
    }
    LKW; BAR;                    // A-write published; safe buffer rotation
    { unsigned short* x = pa; pa = qa; qa = x; }
    { unsigned short* x = pw; pw = qw; qw = x; }
  }

#undef A_ISSUE
#undef A_WRITE
#undef W_ISSUE
#undef RD_BF
#undef RD_AF
#undef MM
#undef VMW
#undef LKW
#undef SB
#undef BAR

  float bs4[4];
#pragma unroll
  for (int n = 0; n < 4; ++n) bs4[n] = bias[cb * 256 + wc * 64 + n * 16 + lq];

#pragma unroll
  for (int m = 0; m < 8; ++m) {
    const int row0 = rb * 256 + wr * 128 + m * 16 + lg * 4;
    const int bn = row0 >> 10, t2 = row0 & 1023;
#pragma unroll
    for (int n = 0; n < 4; ++n) {
      const int col = cb * 256 + wc * 64 + n * 16 + lq;
      const int h = col >> 6, d = col & 63;
      if (kv) {                  // V: V^T layout [bn][h][d][t2], packed store
        u16x4 pv;
#pragma unroll
        for (int j = 0; j < 4; ++j) pv[j] = f2bf(acc[m][n][j] + bs4[n]);
        *(u16x4*)&outv[(((size_t)(bn * kH + h)) * 64 + d) * kT2 + t2] = pv;
      } else {                   // K: kv layout [bn][h][t2][64]
#pragma unroll
        for (int j = 0; j < 4; ++j)
          outv[(((size_t)(bn * kH + h)) * kT2 + t2 + j) * 64 + d] =
              f2bf(acc[m][n][j] + bs4[n]);
      }
    }
  }
}

// ---------------------------------------------------------------------------
// gemm_mixed (128x128, BK=64): used for the small GEMMs (Q: MODE 0, O: MODE 2).
// ---------------------------------------------------------------------------
template<int MODE>
__global__ __launch_bounds__(256, 2) void gemm_mixed(
    const float* __restrict__ A, const unsigned short* __restrict__ Wb,
    const float* __restrict__ bias, void* __restrict__ outv, int nrb) {
  __shared__ __align__(16) unsigned short As[2][128 * 64];   // bf16, 16KB each
  __shared__ __align__(16) unsigned short Bs[3][128 * 64];   // bf16, 16KB each
  const int t = threadIdx.x, lane = t & 63, wave = t >> 6;
  const int w = blockIdx.x;
  const int xcd = w & 7, s = w >> 3;
  const int rb = xcd * (nrb >> 3) + (s >> 2);   // cb-siblings adjacent, same XCD
  const int cb = s & 3;
  const int wr = wave >> 1, wc = wave & 1;
  const int lq = lane & 15, lg = lane >> 4;

  const int arow = t >> 1, ah = (t & 1) * 4;    // staging row, seg-base (0|4)
  const float* aptr = A + (size_t)(rb * 128 + arow) * kF + ah * 8;

  f32x4 acc[4][4];
#pragma unroll
  for (int i = 0; i < 4; ++i)
#pragma unroll
    for (int j = 0; j < 4; ++j) acc[i][j] = f32x4{0.f, 0.f, 0.f, 0.f};

  f32x4 arA[8], arB[8];          // two named A issue-buffers (no runtime idx)
  bf16x8 af[4][2], bfr[4][2];

#define A_LOAD(kb, ar)                                                          \
  do {                                                                          \
    const f32x4* p_ = (const f32x4*)(aptr + (kb) * 64);                         \
    ar[0]=p_[0]; ar[1]=p_[1]; ar[2]=p_[2]; ar[3]=p_[3];                         \
    ar[4]=p_[4]; ar[5]=p_[5]; ar[6]=p_[6]; ar[7]=p_[7];                         \
  } while (0)

#define A_CVT(ar, dst)                                                          \
  do {                                                                          \
    _Pragma("unroll")                                                           \
    for (int j_ = 0; j_ < 4; ++j_)                                              \
      *(bf16x8*)&(dst)[arow * 64 + (((ah + j_) ^ (arow & 7)) << 3)] =           \
          cvt8(ar[2*j_], ar[2*j_+1]);                                           \
  } while (0)

#define W_STAGE2(kb, dst)                                                       \
  do {                                                                          \
    _Pragma("unroll")                                                           \
    for (int i_ = 0; i_ < 4; ++i_) {                                            \
      const int sidx_ = t + i_ * 256;                                           \
      const int row_ = sidx_ >> 3;                                              \
      const int gseg_ = (sidx_ & 7) ^ (row_ & 7);                               \
      async_copy16(Wb + (size_t)(cb * 128 + row_) * kF + (kb) * 64 + gseg_ * 8, \
                   (dst) + (size_t)(i_ * 256 + wave * 64) * 8);                 \
    }                                                                           \
  } while (0)

#define FRAG(Ap, Wp)                                                            \
  do {                                                                          \
    _Pragma("unroll")                                                           \
    for (int m_ = 0; m_ < 4; ++m_) {                                            \
      const int ar_ = wr * 64 + m_ * 16 + lq, x7_ = ar_ & 7;                    \
      af[m_][0] = *(const bf16x8*)&(Ap)[ar_ * 64 + ((lg       ^ x7_) << 3)];    \
      af[m_][1] = *(const bf16x8*)&(Ap)[ar_ * 64 + (((lg + 4) ^ x7_) << 3)];    \
    }                                                                           \
    _Pragma("unroll")                                                           \
    for (int n_ = 0; n_ < 4; ++n_) {                                            \
      const int br_ = wc * 64 + n_ * 16 + lq, x7_ = br_ & 7;                    \
      bfr[n_][0] = *(const bf16x8*)&(Wp)[br_ * 64 + ((lg       ^ x7_) << 3)];   \
      bfr[n_][1] = *(const bf16x8*)&(Wp)[br_ * 64 + (((lg + 4) ^ x7_) << 3)];   \
    }                                                                           \
  } while (0)

#define MFMA8                                                                   \
  do {                                                                          \
    _Pragma("unroll")                                                           \
    for (int kk_ = 0; kk_ < 2; ++kk_)                                           \
      _Pragma("unroll")                                                         \
      for (int m_ = 0; m_ < 4; ++m_)                                            \
        _Pragma("unroll")                                                       \
        for (int n_ = 0; n_ < 4; ++n_)                                          \
          acc[m_][n_] = __builtin_amdgcn_mfma_f32_16x16x32_bf16(                \
              af[m_][kk_], bfr[n_][kk_], acc[m_][n_], 0, 0, 0);                 \
  } while (0)

#define VMW(n) asm volatile("s_waitcnt vmcnt(" #n ")" ::: "memory")
#define LKW    asm volatile("s_waitcnt lgkmcnt(0)" ::: "memory")
#define BAR    do { __builtin_amdgcn_s_barrier(); __builtin_amdgcn_sched_barrier(0); } while (0)

  // prologue: A0->arA, A1->arB, W0, W1 (24 in flight)
  A_LOAD(0, arA); A_LOAD(1, arB);
  W_STAGE2(0, Bs[0]); W_STAGE2(1, Bs[1]);
  VMW(16);                       // A0 landed
  A_CVT(arA, As[0]);
  LKW; BAR;
  // iter 0
  A_LOAD(2, arA); W_STAGE2(2, Bs[2]);
  FRAG(As[0], Bs[0]); MFMA8;
  VMW(12); A_CVT(arB, As[1]); LKW; BAR;
  // iter 1
  A_LOAD(3, arB); W_STAGE2(3, Bs[0]);
  FRAG(As[1], Bs[1]); MFMA8;
  VMW(12); A_CVT(arA, As[0]); LKW; BAR;
  // iter 2
  A_LOAD(4, arA); W_STAGE2(4, Bs[1]);
  FRAG(As[0], Bs[2]); MFMA8;
  VMW(12); A_CVT(arB, As[1]); LKW; BAR;
  // iter 3
  A_LOAD(5, arB); W_STAGE2(5, Bs[2]);
  FRAG(As[1], Bs[0]); MFMA8;
  VMW(12); A_CVT(arA, As[0]); LKW; BAR;
  // iter 4
  A_LOAD(6, arA); W_STAGE2(6, Bs[0]);
  FRAG(As[0], Bs[1]); MFMA8;
  VMW(12); A_CVT(arB, As[1]); LKW; BAR;
  // iter 5
  A_LOAD(7, arB); W_STAGE2(7, Bs[1]);
  FRAG(As[1], Bs[2]); MFMA8;
  VMW(12); A_CVT(arA, As[0]); LKW; BAR;
  // iter 6
  FRAG(As[0], Bs[0]); MFMA8;
  VMW(0); A_CVT(arB, As[1]); LKW; BAR;
  // iter 7
  FRAG(As[1], Bs[1]); MFMA8;

#undef A_LOAD
#undef A_CVT
#undef W_STAGE2
#undef FRAG
#undef MFMA8
#undef VMW
#undef LKW
#undef BAR

  float bs[4];
#pragma unroll
  for (int n2 = 0; n2 < 4; ++n2) bs[n2] = bias[cb*128 + wc*64 + n2*16 + lq];

#pragma unroll
  for (int m = 0; m < 4; ++m) {
#pragma unroll
    for (int n2 = 0; n2 < 4; ++n2) {
      const int col = cb*128 + wc*64 + n2*16 + lq;
      const int row0 = rb*128 + wr*64 + m*16 + lg*4;
#pragma unroll
      for (int j = 0; j < 4; ++j) {
        const int row = row0 + j;
        const float v = acc[m][n2][j] + bs[n2];
        if (MODE == 2) {
          ((float*)outv)[(size_t)row * kF + col] = v;
        } else {
          const int h = col >> 6, d = col & 63;
          const int b = row >> 8, t1i = row & 255;
          ((unsigned short*)outv)[(((size_t)(b * kH + h)) * kT1 + t1i) * 64 + d] = f2bf(v);
        }
      }
    }
  }
}

// ---------------------------------------------------------------------------
// Stage-1 flash attention, q-split x2: one block per (b,n,h,qb), 8 waves x
// 16 q-rows = 128 q-rows/block. NO-MAX softmax, lane-local l1, 3-buffer K/V
// (52 KB -> 3 blocks/CU), stage-at-bottom + wait-before-barrier vmcnt(2).
// grid = 1024, XCD-swizzled so qb-siblings share an XCD (K/V L2 reuse).
// ---------------------------------------------------------------------------
__global__ __launch_bounds__(512, 4) void attn_kernel(
    const unsigned short* __restrict__ qh, const unsigned short* __restrict__ kh,
    const unsigned short* __restrict__ vt, const int* __restrict__ mask_audio,
    unsigned short* __restrict__ phone) {
  __shared__ __align__(16) unsigned short Ks[3][64 * 64];   // 3 x 8 KB
  __shared__ __align__(16) unsigned short Vs[3][64 * 64];   // 3 x 8 KB
  __shared__ float Mbias[1024];                              // 4 KB
  const int t = threadIdx.x;
  const int lane = t & 63, wave = t >> 6;
  const int lq = lane & 15, lg = lane >> 4;
  const int w = blockIdx.x;
  const int swz = (w & 7) * 128 + (w >> 3);     // bijective (1024 % 8 == 0)
  const int qb = swz & 1, bnh = swz >> 1;
  const int h = bnh & 7, n = (bnh >> 3) & 3, b = bnh >> 5;
  const size_t qbase  = ((size_t)(b * kH + h)) * kT1 * 64;
  const size_t kvbase = ((size_t)((b * kN + n) * kH + h)) * kT2 * 64;  // same for vt
  const int* mbase = mask_audio + (size_t)(b * kN + n) * kT2;

  const int srow = (wave << 3) + (lane >> 3);   // staging row 0..63
  const int sgx = ((lane & 7) ^ (srow & 7)) << 3;  // pre-swizzled global seg (u16)

#define STAGE_KV(c, kd, vd)                                                       \
  do {                                                                            \
    async_copy16(kh + kvbase + ((size_t)(((c) << 6) + srow) << 6) + sgx,          \
                 (kd) + (wave << 9));                                             \
    async_copy16(vt + kvbase + ((size_t)srow << 10) + ((c) << 6) + sgx,           \
                 (vd) + (wave << 9));                                             \
  } while (0)

  { // mask -> additive f32 bias, loaded once for all 16 chunks
    const int i0 = t * 2;
    const int m0 = mbase[i0], m1 = mbase[i0 + 1];
    Mbias[i0]     = m0 ? 0.f : -1e30f;
    Mbias[i0 + 1] = m1 ? 0.f : -1e30f;
  }

  // Q fragments in registers (16 rows per wave; reused all 16 chunks)
  bf16x8 qf0, qf1;
  {
    const unsigned short* qp = qh + qbase +
        ((size_t)((qb << 7) + (wave << 4) + lq) << 6);
    qf0 = *(const bf16x8*)(qp + (lg << 3));
    qf1 = *(const bf16x8*)(qp + 32 + (lg << 3));
  }

  unsigned short *kb0 = Ks[0], *kb1 = Ks[1], *kb2 = Ks[2];
  unsigned short *vb0 = Vs[0], *vb1 = Vs[1], *vb2 = Vs[2];

  // prologue: stage chunks 0,1 (4 loads in flight); drain mask ds_writes
  STAGE_KV(0, kb0, vb0);
  STAGE_KV(1, kb1, vb1);
  asm volatile("s_waitcnt lgkmcnt(0)" ::: "memory");

  f32x4 of[4];
  float l1 = 0.f;
#pragma unroll
  for (int fd = 0; fd < 4; ++fd) of[fd] = f32x4{0.f, 0.f, 0.f, 0.f};
  const float sc2 = kSCALE * kLOG2E;

#pragma unroll 1
  for (int c = 0; c < 16; ++c) {
    // wait-before-barrier: retire chunk c's 2 loads (mine), publish via barrier
    if (c < 15) asm volatile("s_waitcnt vmcnt(2)" ::: "memory");
    else        asm volatile("s_waitcnt vmcnt(0)" ::: "memory");
    __builtin_amdgcn_s_barrier();
    __builtin_amdgcn_sched_barrier(0);

    const float* mrow = Mbias + (c << 6);

    f32x4 sT[4];
#pragma unroll
    for (int kt = 0; kt < 4; ++kt) {
      const int kr = kt * 16 + lq, x7 = kr & 7;
      const bf16x8 kf0 = *(const bf16x8*)&kb0[kr * 64 + ((lg       ^ x7) << 3)];
      const bf16x8 kf1 = *(const bf16x8*)&kb0[kr * 64 + (((lg + 4) ^ x7) << 3)];
      f32x4 sv = f32x4{0.f, 0.f, 0.f, 0.f};
      sv = __builtin_amdgcn_mfma_f32_16x16x32_bf16(kf0, qf0, sv, 0, 0, 0);
      sv = __builtin_amdgcn_mfma_f32_16x16x32_bf16(kf1, qf1, sv, 0, 0, 0);
      sT[kt] = sv;   // lane: q=lq, key = kt*16 + lg*4 + j
    }
    // no-max softmax: P = exp2(scale*s + bias); bounded, no overflow risk
    float pf[16];
#pragma unroll
    for (int kt = 0; kt < 4; ++kt) {
      const f32x4 mk = *(const f32x4*)&mrow[kt * 16 + lg * 4];
#pragma unroll
      for (int j = 0; j < 4; ++j)
        pf[kt*4+j] = exp2f(fmaf(sT[kt][j], sc2, mk[j]));
    }
    const float a0 = (pf[0] + pf[1]) + (pf[2] + pf[3]);
    const float a1 = (pf[4] + pf[5]) + (pf[6] + pf[7]);
    const float a2 = (pf[8] + pf[9]) + (pf[10] + pf[11]);
    const float a3 = (pf[12] + pf[13]) + (pf[14] + pf[15]);
    l1 += (a0 + a1) + (a2 + a3);               // lane-local; reduced at end
    // repack P (S^T layout) -> PV A-fragments (native casts -> cvt_pk)
    unsigned pk[8];
#pragma unroll
    for (int kt = 0; kt < 4; ++kt) {
      pk[2*kt]   = (unsigned)f2bf(pf[4*kt+0]) | ((unsigned)f2bf(pf[4*kt+1]) << 16);
      pk[2*kt+1] = (unsigned)f2bf(pf[4*kt+2]) | ((unsigned)f2bf(pf[4*kt+3]) << 16);
    }
    unsigned am0[4], am1[4];
#if HAVE_PERMLANE
    {
      auto x0p = __builtin_amdgcn_permlane32_swap((int)pk[0], (int)pk[2], false, false);
      auto y0p = __builtin_amdgcn_permlane16_swap(x0p[0], x0p[1], false, false);
      am0[0] = (unsigned)y0p[0]; am0[2] = (unsigned)y0p[1];
      auto x1p = __builtin_amdgcn_permlane32_swap((int)pk[1], (int)pk[3], false, false);
      auto y1p = __builtin_amdgcn_permlane16_swap(x1p[0], x1p[1], false, false);
      am0[1] = (unsigned)y1p[0]; am0[3] = (unsigned)y1p[1];
      auto x2p = __builtin_amdgcn_permlane32_swap((int)pk[4], (int)pk[6], false, false);
      auto y2p = __builtin_amdgcn_permlane16_swap(x2p[0], x2p[1], false, false);
      am1[0] = (unsigned)y2p[0]; am1[2] = (unsigned)y2p[1];
      auto x3p = __builtin_amdgcn_permlane32_swap((int)pk[5], (int)pk[7], false, false);
      auto y3p = __builtin_amdgcn_permlane16_swap(x3p[0], x3p[1], false, false);
      am1[1] = (unsigned)y3p[0]; am1[3] = (unsigned)y3p[1];
    }
#else
    {
      const int srcbase = (2 * (lg & 1)) * 16 + lq;
#pragma unroll
      for (int u = 0; u < 4; ++u) {
        const int src = srcbase + (u >> 1) * 16;
        const unsigned va0 = __shfl(pk[(u & 1)],     src);
        const unsigned vb0s = __shfl(pk[2 + (u & 1)], src);
        am0[u] = (lg & 2) ? vb0s : va0;
        const unsigned va1 = __shfl(pk[4 + (u & 1)], src);
        const unsigned vb1s = __shfl(pk[6 + (u & 1)], src);
        am1[u] = (lg & 2) ? vb1s : va1;
      }
    }
#endif
    union { unsigned u[4]; bf16x8 v; } A0, A1;
#pragma unroll
    for (int u = 0; u < 4; ++u) { A0.u[u] = am0[u]; A1.u[u] = am1[u]; }
#pragma unroll
    for (int fd = 0; fd < 4; ++fd) {
      const int d = fd * 16 + lq, x7d = d & 7;
      const bf16x8 vB0 = *(const bf16x8*)&vb0[d * 64 + ((lg       ^ x7d) << 3)];
      const bf16x8 vB1 = *(const bf16x8*)&vb0[d * 64 + (((lg + 4) ^ x7d) << 3)];
      of[fd] = __builtin_amdgcn_mfma_f32_16x16x32_bf16(A0.v, vB0, of[fd], 0, 0, 0);
      of[fd] = __builtin_amdgcn_mfma_f32_16x16x32_bf16(A1.v, vB1, of[fd], 0, 0, 0);
    }

    // stage chunk c+2 at bottom (covers ~1.5 iterations before its wait)
    if (c < 14) STAGE_KV(c + 2, kb2, vb2);
    { unsigned short* x = kb0; kb0 = kb1; kb1 = kb2; kb2 = x; }
    { unsigned short* x = vb0; vb0 = vb1; vb1 = vb2; vb2 = x; }
  }
#undef STAGE_KV

  // epilogue: cross-lane l1 reduce (once), then normalize + store
  l1 += __shfl_xor(l1, 16);
  l1 += __shfl_xor(l1, 32);
  const size_t phbase = ((size_t)((b * kN + n) * kH + h)) * kT1 * 64;
  const float li0 = 1.f / __shfl(l1, lg*4 + 0);
  const float li1 = 1.f / __shfl(l1, lg*4 + 1);
  const float li2 = 1.f / __shfl(l1, lg*4 + 2);
  const float li3 = 1.f / __shfl(l1, lg*4 + 3);
#pragma unroll
  for (int fd = 0; fd < 4; ++fd) {
    const int d = fd * 16 + lq;
    const size_t rowb = phbase +
        (size_t)((qb << 7) + (wave << 4) + lg*4) * 64 + d;
    phone[rowb]       = f2bf(of[fd][0] * li0);
    phone[rowb + 64]  = f2bf(of[fd][1] * li1);
    phone[rowb + 128] = f2bf(of[fd][2] * li2);
    phone[rowb + 192] = f2bf(of[fd][3] * li3);
  }
}

// ---------------------------------------------------------------------------
// Stage-2: per (b,t1,h) wave: masked softmax over N=4 candidates.
// ---------------------------------------------------------------------------
__global__ __launch_bounds__(256) void stage2_kernel(
    const unsigned short* __restrict__ qh, const unsigned short* __restrict__ phone,
    const int* __restrict__ mask_spk, float* __restrict__ x) {
  const int t = threadIdx.x, lane = t & 63, wave = t >> 6;
  const int wid = blockIdx.x * 4 + wave;
  const int h = wid & 7;
  const int bt = wid >> 3;
  const int t1i = bt & 255, b = bt >> 8;
  const int d = lane;
  const float q = bf2f(qh[(((size_t)(b * kH + h)) * kT1 + t1i) * 64 + d]);
  float ph[4], ss[4];
#pragma unroll
  for (int n = 0; n < 4; ++n) {
    ph[n] = bf2f(phone[(((size_t)((b * kN + n) * kH + h)) * kT1 + t1i) * 64 + d]);
    float sv = q * ph[n];
#pragma unroll
    for (int o = 1; o < 64; o <<= 1) sv += __shfl_xor(sv, o);
    ss[n] = sv * kSCALE;
  }
  int msk[4];
#pragma unroll
  for (int n = 0; n < 4; ++n) msk[n] = mask_spk[b * kN + n];
  float mx = -INFINITY;
#pragma unroll
  for (int n = 0; n < 4; ++n) if (msk[n]) mx = fmaxf(mx, ss[n]);
  float e[4], sum = 0.f;
#pragma unroll
  for (int n = 0; n < 4; ++n) { const float v = msk[n] ? __expf(ss[n] - mx) : 0.f; e[n] = v; sum += v; }
  float xo = 0.f;
#pragma unroll
  for (int n = 0; n < 4; ++n) xo += e[n] * ph[n];
  xo /= sum;
  x[((size_t)(b * kT1 + t1i)) * kF + h * 64 + d] = xo;
}

}  // namespace

// ---------------------------------------------------------------------------
extern "C" void kernel_launch(void* const* d_in, const int* in_sizes, int n_in,
                              void* d_out, int out_size, void* d_ws, size_t ws_size,
                              hipStream_t stream) {
  (void)in_sizes; (void)n_in; (void)out_size; (void)ws_size;
  const float* query = (const float*)d_in[0];
  const float* key   = (const float*)d_in[1];
  const float* value = (const float*)d_in[2];
  const int* mask_audio = (const int*)d_in[3];
  const int* mask_spk   = (const int*)d_in[4];
  const float* Wq = (const float*)d_in[5];  const float* bq = (const float*)d_in[6];
  const float* Wk = (const float*)d_in[7];  const float* bk = (const float*)d_in[8];
  const float* Wv = (const float*)d_in[9];  const float* bv = (const float*)d_in[10];
  const float* Wo = (const float*)d_in[11]; const float* bo = (const float*)d_in[12];
  float* out = (float*)d_out;

  // workspace layout (~158 MB)
  unsigned short* qws  = (unsigned short*)d_ws;                       // 2,097,152 u16
  unsigned short* kws  = qws  + (size_t)kB * kH * kT1 * 64;           // 33,554,432 u16
  unsigned short* vws  = kws  + (size_t)kB * kN * kH * kT2 * 64;      // 33,554,432 u16 (V^T)
  unsigned short* phws = vws  + (size_t)kB * kN * kH * kT2 * 64;      // 8,388,608 u16
  float*          xws  = (float*)(phws + (size_t)kB * kN * kH * kT1 * 64);  // 2,097,152 f32
  unsigned short* wqb  = (unsigned short*)(xws + (size_t)kB * kT1 * kF);
  unsigned short* wkb  = wqb + (size_t)kF * kF;
  unsigned short* wvb  = wkb + (size_t)kF * kF;
  unsigned short* wob  = wvb + (size_t)kF * kF;

  convert_w<<<1024, 256, 0, stream>>>(Wq, Wk, Wv, Wo, wqb, wkb, wvb, wob);
  gemm_mixed<0><<<kB * kT1 / 128 * 4, 256, 0, stream>>>(query, wqb, bq, qws, kB * kT1 / 128);
  gemm256_kv<<<kB * kN * kT2 / 256 * 4, 512, 0, stream>>>(
      key, wkb, bk, kws, value, wvb, bv, vws);
  attn_kernel<<<kB * kN * kH * 2, 512, 0, stream>>>(qws, kws, vws, mask_audio, phws);
  stage2_kernel<<<kB * kT1 * kH / 4, 256, 0, stream>>>(qws, phws, mask_spk, xws);
  gemm_mixed<2><<<kB * kT1 / 128 * 4, 256, 0, stream>>>(xws, wob, bo, out, kB * kT1 / 128);
}